// Round 10
// baseline (7490.526 us; speedup 1.0000x reference)
//
#include <hip/hip_runtime.h>
#include <math.h>

#define T_   256
#define C_   16

typedef float    f32x4  __attribute__((ext_vector_type(4)));
typedef float    f32x16 __attribute__((ext_vector_type(16)));
typedef _Float16 f16x8  __attribute__((ext_vector_type(8)));
typedef short    short8 __attribute__((ext_vector_type(8)));
typedef int      i32x4  __attribute__((ext_vector_type(4)));
typedef unsigned long long ULL;

__device__ __forceinline__ float sigf(float x)  { return 1.0f/(1.0f + __expf(-x)); }
__device__ __forceinline__ float tanhf_(float x){ return 1.0f - 2.0f/(1.0f + __expf(2.0f*x)); }

__device__ __forceinline__ ushort f16b(float w) {
  _Float16 h = (_Float16)w; return __builtin_bit_cast(ushort, h);
}
__device__ __forceinline__ float f16f(ushort b) {
  return (float)__builtin_bit_cast(_Float16, b);
}

// LLC-coherent 16B load (bypass L1/L2 both ways; no fences needed)
#define LLCLD(dst, base, OFF) \
  asm volatile("global_load_dwordx4 %0, %1, off offset:%c2 sc0 sc1" \
               : "=v"(dst) : "v"(base), "n"(OFF) : "memory")

// ================= k_prep: ALL weight prep in one node =================
struct PrepArgs {
  const float *cl_emb, *c_wih, *c_b, *c_whh;
  const float *wih[6];
  const float *bb[6];
  ushort *Wh[6];
  float *preT, *whhc, *bP;
  int *barr;
};

__global__ void __launch_bounds__(256) k_prep(PrepArgs A) {
  __shared__ float e[64];
  int b = blockIdx.x, tid = threadIdx.x;
  if (b == 0) A.barr[tid] = 0;   // zero all 256 barrier slots every launch/replay
  if (b < 100) {
    if (tid < 64) e[tid] = A.cl_emb[b*64 + tid];
    __syncthreads();
    float ss = 0.f;
    #pragma unroll 8
    for (int k = 0; k < 64; ++k) ss += e[k]*e[k];
    float nn = sqrtf(ss);
    float scl = (nn > 1.0f) ? 1.0f/nn : 1.0f;
    int u = tid >> 2, q = tid & 3;
    const float* wrow = A.c_wih + (q*64 + u)*64;
    float acc = 0.f;
    #pragma unroll 8
    for (int k = 0; k < 64; ++k) acc += e[k]*wrow[k];
    A.preT[b*256 + tid] = A.c_b[q*64 + u] + scl*acc;
  } else if (b < 164) {
    int i = (b - 100)*256 + tid;
    int k = i >> 8, rem = i & 255, u = rem >> 2, q = rem & 3;
    A.whhc[i] = A.c_whh[(q*64 + u)*64 + k];
  } else if (b < 212) {
    int i = (b - 164)*256 + tid;
    int ld = i >> 11, j = i & 2047, u = j >> 2, q = j & 3;
    A.bP[i] = A.bb[ld][q*512 + u];
  } else {
    int idx = b - 212;
    int ld, off, D;
    if (idx < 1280) { ld = idx / 640; off = idx - ld*640; D = 320; }
    else { idx -= 1280; ld = 2 + (idx >> 11); off = idx & 2047; D = 1024; }
    int i4 = off*256 + tid;
    int D4 = D >> 2;
    int g4 = i4 / D4, k4 = i4 - g4*D4;
    int u = g4 >> 2, q = g4 & 3;
    float4 v = *(const float4*)(A.wih[ld] + (size_t)(q*512 + u)*D + (k4 << 2));
    ushort4 hh;
    hh.x = f16b(v.x); hh.y = f16b(v.y); hh.z = f16b(v.z); hh.w = f16b(v.w);
    *(ushort4*)(A.Wh[ld] + (size_t)g4*D + (k4 << 2)) = hh;
  }
}

// ================= k_wordchar: word emb + char LSTM =================
__global__ void __launch_bounds__(256) k_wordchar(const int* __restrict__ words,
    const int* __restrict__ chars, const float* __restrict__ wl_emb,
    const float* __restrict__ preT, const float* __restrict__ whhc,
    ushort* __restrict__ Xf) {
  __shared__ float sh[2*64*68];
  int b = blockIdx.x, tid = threadIdx.x;
  if (b >= 256) {
    int tok = b - 256;
    int row = words[tok];
    float e = wl_emb[(size_t)row*256 + tid];
    float ss = e*e;
    #pragma unroll
    for (int o = 32; o; o >>= 1) ss += __shfl_xor(ss, o, 64);
    int lane = tid & 63, wv = tid >> 6;
    if (lane == 0) sh[wv] = ss;
    __syncthreads();
    if (tid == 0) {
      float s2 = sh[0] + sh[1] + sh[2] + sh[3];
      float nn = sqrtf(s2);
      sh[4] = (nn > 1.0f) ? 1.0f/nn : 1.0f;
    }
    __syncthreads();
    Xf[(size_t)tok*320 + tid] = f16b(e*sh[4]);
    return;
  }
  int u = tid & 63, sg = tid >> 6;
  int sbase = b*64 + sg*16;
  float c[16];
  float4 acc[16];
  for (int t = 0; t < C_; ++t) {
    #pragma unroll
    for (int i = 0; i < 16; ++i) {
      int ch = chars[(sbase + i)*C_ + t];
      acc[i] = *(const float4*)(preT + ch*256 + (u << 2));
    }
    if (t > 0) {
      const float* hp = sh + ((t - 1) & 1)*(64*68) + (sg << 4);
      #pragma unroll 2
      for (int k = 0; k < 64; ++k) {
        float4 w = *(const float4*)(whhc + (k << 8) + (u << 2));
        const float* hr = hp + k*68;
        float4 h0 = *(const float4*)(hr + 0);
        float4 h1 = *(const float4*)(hr + 4);
        float4 h2 = *(const float4*)(hr + 8);
        float4 h3 = *(const float4*)(hr + 12);
        float hv[16] = {h0.x,h0.y,h0.z,h0.w, h1.x,h1.y,h1.z,h1.w,
                        h2.x,h2.y,h2.z,h2.w, h3.x,h3.y,h3.z,h3.w};
        #pragma unroll
        for (int i = 0; i < 16; ++i) {
          acc[i].x += w.x*hv[i]; acc[i].y += w.y*hv[i];
          acc[i].z += w.z*hv[i]; acc[i].w += w.w*hv[i];
        }
      }
    }
    float* hw = sh + (t & 1)*(64*68);
    #pragma unroll
    for (int i = 0; i < 16; ++i) {
      float ig = sigf(acc[i].x), fg = sigf(acc[i].y);
      float gg = tanhf_(acc[i].z), og = sigf(acc[i].w);
      float cc = (t == 0) ? (ig*gg) : (fg*c[i] + ig*gg);
      c[i] = cc;
      float hh = og*tanhf_(cc);
      hw[u*68 + (sg << 4) + i] = hh;
      if (t == C_-1) Xf[(size_t)(sbase + i)*320 + 256 + u] = f16b(hh);
    }
    __syncthreads();
  }
}

// ================= pregate GEMM: global_load_lds + src-side XOR swizzle, fp16 W =================
// preg layout: [dir][s][g16=0..127][n=0..63][16 floats]
__global__ void __launch_bounds__(256) k_gemm(const ushort* __restrict__ Xf,
    const ushort* __restrict__ Whf, const ushort* __restrict__ Whb,
    const float* __restrict__ bPf, const float* __restrict__ bPb,
    float* __restrict__ preg, int D, int t0, int TCc) {
  int dir = blockIdx.z;
  const ushort* WhD = dir ? Whb : Whf;
  const float*  bPD = dir ? bPb : bPf;
  int mt = blockIdx.x, nt = blockIdx.y;
  int tid = threadIdx.x;

  __shared__ __align__(16) ushort As[128*64], Bh[128*64];
  int lane = tid & 63, wid = tid >> 6;
  int wm = wid >> 1, wn = wid & 1;
  int l15 = lane & 15, l4 = lane >> 4;

  const ushort *asrc[4], *bhsrc[4];
  ushort *adst[4], *bhdst[4];
  #pragma unroll
  for (int c = 0; c < 4; ++c) {
    int idx = c*256 + tid;
    int row = idx >> 3, ch = idx & 7;
    int chs = ch ^ (row & 7);                 // source-side swizzle (involution)
    int r = mt*128 + row, s = r >> 6, n = r & 63;
    int ttt = dir ? (T_ - 1 - (t0 + s)) : (t0 + s);
    asrc[c]  = Xf  + ((size_t)n*T_ + ttt)*D + chs*8;
    bhsrc[c] = WhD + (size_t)(nt*128 + row)*D + chs*8;
    adst[c]  = As + idx*8; bhdst[c] = Bh + idx*8;
  }
  int sw = l15 & 7;
  int rA[4], rB[4];
  #pragma unroll
  for (int f = 0; f < 4; ++f) {
    rA[f] = (wm*64 + f*16 + l15) << 6;
    rB[f] = (wn*64 + f*16 + l15) << 6;
  }

  f32x4 acc[4][4];
  #pragma unroll
  for (int a = 0; a < 4; ++a)
    #pragma unroll
    for (int bq = 0; bq < 4; ++bq) acc[a][bq] = (f32x4){0.f,0.f,0.f,0.f};

  for (int k0 = 0; k0 < D; k0 += 64) {
    __syncthreads();
    #pragma unroll
    for (int c = 0; c < 4; ++c) {
      __builtin_amdgcn_global_load_lds(
        (const __attribute__((address_space(1))) void*)(asrc[c] + k0),
        (__attribute__((address_space(3))) void*)adst[c], 16, 0, 0);
      __builtin_amdgcn_global_load_lds(
        (const __attribute__((address_space(1))) void*)(bhsrc[c] + k0),
        (__attribute__((address_space(3))) void*)bhdst[c], 16, 0, 0);
    }
    asm volatile("s_waitcnt vmcnt(0)" ::: "memory");
    __syncthreads();
    #pragma unroll
    for (int ks = 0; ks < 2; ++ks) {
      int fo = (((ks << 2) + l4) ^ sw) << 3;   // swizzled 16B-chunk read
      f16x8 av[4], bhv[4];
      #pragma unroll
      for (int mf = 0; mf < 4; ++mf)
        av[mf] = __builtin_bit_cast(f16x8, *(const short8*)(As + rA[mf] + fo));
      #pragma unroll
      for (int nf = 0; nf < 4; ++nf)
        bhv[nf] = __builtin_bit_cast(f16x8, *(const short8*)(Bh + rB[nf] + fo));
      #pragma unroll
      for (int mf = 0; mf < 4; ++mf)
        #pragma unroll
        for (int nf = 0; nf < 4; ++nf)
          acc[mf][nf] = __builtin_amdgcn_mfma_f32_16x16x32_f16(av[mf], bhv[nf], acc[mf][nf], 0,0,0);
    }
  }
  float bias[4];
  #pragma unroll
  for (int nf = 0; nf < 4; ++nf) bias[nf] = bPD[nt*128 + wn*64 + nf*16 + l15];
  #pragma unroll
  for (int mf = 0; mf < 4; ++mf)
    #pragma unroll
    for (int nf = 0; nf < 4; ++nf) {
      int g16 = nt*8 + wn*4 + nf;
      #pragma unroll
      for (int rr = 0; rr < 4; ++rr) {
        int r = mt*128 + wm*64 + mf*16 + (l4 << 2) + rr;
        int s = r >> 6, n = r & 63;
        preg[((size_t)(dir*TCc + s)*128 + g16)*1024 + n*16 + l15] = acc[mf][nf][rr] + bias[nf];
      }
    }
}

// ================= main recurrence: 64 blocks x 4 AUTONOMOUS waves =================
// block bi owns units [bi*8, bi*8+8). wave w: dir = w>>1, n-half nh = w&1.
// Per-(dir,nh) barrier group of 64 waves; NO __syncthreads in the step loop.
__global__ void __launch_bounds__(256, 1) k_rec(const float* __restrict__ preg,
    const float* __restrict__ whhf, const float* __restrict__ whhb,
    ushort* __restrict__ XO, ushort* __restrict__ hF, float* __restrict__ cst,
    int* __restrict__ barr, int t0, int TCc, int ebase,
    int doCls, const float* __restrict__ Wc, const float* __restrict__ bc,
    float* __restrict__ outp) {
  __shared__ float red[64][4][3];
  int bi = blockIdx.x;                   // unit slice [bi*8, bi*8+8)
  int tid = threadIdx.x, w = tid >> 6, l = tid & 63;
  int dir = w >> 1, nh = w & 1;
  const float* whh = dir ? whhb : whhf;
  int l31 = l & 31, l5 = l >> 5;
  int q = l31 & 3, ul = l31 >> 2;
  int u0 = bi*8;
  int n_ = nh*32 + l31;
  int grp = (dir*2 + nh)*64;             // barrier group base

  // ---- Whh slice -> registers (fp16): A rows = 8 units x 4 gates ----
  f16x8 ah[32];
  {
    const float* wr = whh + ((size_t)(q*512 + u0 + ul))*512 + l5*8;
    #pragma unroll
    for (int ks = 0; ks < 32; ++ks) {
      float4 w0 = *(const float4*)(wr + ks*16);
      float4 w1 = *(const float4*)(wr + ks*16 + 4);
      float wf[8] = {w0.x,w0.y,w0.z,w0.w, w1.x,w1.y,w1.z,w1.w};
      short8 h8;
      #pragma unroll
      for (int j = 0; j < 8; ++j) h8[j] = (short)f16b(wf[j]);
      ah[ks] = __builtin_bit_cast(f16x8, h8);
    }
  }
  float cv[4];
  #pragma unroll
  for (int e = 0; e < 4; ++e)
    cv[e] = (t0 == 0) ? 0.f : cst[(size_t)(dir*64 + n_)*512 + u0 + 2*e + l5];

  // prologue: preg for s=0 (acc reg block e holds gates q=0..3 of unit 2e+l5)
  f32x16 accA;
  {
    const float* pb = preg + (size_t)(dir*TCc)*131072;
    #pragma unroll
    for (int e = 0; e < 4; ++e) {
      f32x4 v = *(const f32x4*)(pb + (size_t)(bi*2 + (e>>1))*1024 + n_*16 + ((e&1)*2 + l5)*4);
      accA[4*e+0]=v[0]; accA[4*e+1]=v[1]; accA[4*e+2]=v[2]; accA[4*e+3]=v[3];
    }
  }

  #pragma unroll 1
  for (int s = 0; s < TCc; ++s) {
    int t = t0 + s;
    int tt = dir ? (T_ - 1 - t) : t;
    f32x16 accB = (f32x16)(0.f);
    if (t > 0) {
      const ushort* hb = hF + (size_t)((dir<<1) | ((t-1)&1))*32768 + (size_t)n_*512 + l5*8;
      f16x8 h0[8], h1[8], h2[8];
      #pragma unroll
      for (int j = 0; j < 8; ++j) LLCLD(h0[j], hb, (0+j)*32);
      #pragma unroll
      for (int j = 0; j < 8; ++j) LLCLD(h1[j], hb, (8+j)*32);
      asm volatile("s_waitcnt vmcnt(8)" ::: "memory");
      __builtin_amdgcn_sched_barrier(0);
      #pragma unroll
      for (int j = 0; j < 8; ++j) LLCLD(h2[j], hb, (16+j)*32);
      #pragma unroll
      for (int j = 0; j < 8; ++j)
        accA = __builtin_amdgcn_mfma_f32_32x32x16_f16(ah[j], h0[j], accA, 0,0,0);
      asm volatile("s_waitcnt vmcnt(8)" ::: "memory");
      __builtin_amdgcn_sched_barrier(0);
      #pragma unroll
      for (int j = 0; j < 8; ++j) LLCLD(h0[j], hb, (24+j)*32);
      #pragma unroll
      for (int j = 0; j < 8; ++j)
        accA = __builtin_amdgcn_mfma_f32_32x32x16_f16(ah[8+j], h1[j], accA, 0,0,0);
      asm volatile("s_waitcnt vmcnt(8)" ::: "memory");
      __builtin_amdgcn_sched_barrier(0);
      #pragma unroll
      for (int j = 0; j < 8; ++j)
        accB = __builtin_amdgcn_mfma_f32_32x32x16_f16(ah[16+j], h2[j], accB, 0,0,0);
      asm volatile("s_waitcnt vmcnt(0)" ::: "memory");
      __builtin_amdgcn_sched_barrier(0);
      #pragma unroll
      for (int j = 0; j < 8; ++j)
        accB = __builtin_amdgcn_mfma_f32_32x32x16_f16(ah[24+j], h0[j], accB, 0,0,0);
    }
    // gates + intra-wave transpose (shfl across the l5 pair; no LDS, no barriers)
    uint outw[4];
    #pragma unroll
    for (int e = 0; e < 4; ++e) {
      float ig = sigf(accA[4*e+0] + accB[4*e+0]);
      float fg = sigf(accA[4*e+1] + accB[4*e+1]);
      float gg = tanhf_(accA[4*e+2] + accB[4*e+2]);
      float og = sigf(accA[4*e+3] + accB[4*e+3]);
      float c = (t == 0) ? (ig*gg) : (fg*cv[e] + ig*gg);
      cv[e] = c;
      float h = og*tanhf_(c);
      uint mine = (uint)f16b(h);
      uint theirs = (uint)__shfl_xor((int)mine, 32, 64);
      outw[e] = l5 ? ((theirs & 0xffffu) | (mine << 16)) : ((mine & 0xffffu) | (theirs << 16));
    }
    // l5=0 lanes: hF via LLC write-through; l5=1 lanes: XO plain (next-kernel consumer)
    if (l5 == 0) {
      ushort* hdst = hF + (size_t)((dir<<1)|(t&1))*32768 + (size_t)n_*512 + u0;
      i32x4 vv; vv[0] = (int)outw[0]; vv[1] = (int)outw[1]; vv[2] = (int)outw[2]; vv[3] = (int)outw[3];
      asm volatile("global_store_dwordx4 %0, %1, off sc0 sc1" :: "v"(hdst), "v"(vv) : "memory");
    } else if (XO) {
      uint4 vv; vv.x = outw[0]; vv.y = outw[1]; vv.z = outw[2]; vv.w = outw[3];
      *(uint4*)(XO + (size_t)n_*262144 + (size_t)tt*1024 + dir*512 + u0) = vv;
    }
    asm volatile("s_waitcnt vmcnt(0)" ::: "memory");   // per-wave release drain
    int epoch = ebase + s + 1;
    if (l == 0)
      __hip_atomic_store(&barr[grp + bi], epoch, __ATOMIC_RELAXED, __HIP_MEMORY_SCOPE_AGENT);
    // prefetch next step's preg while peers arrive
    if (s + 1 < TCc) {
      const float* pb = preg + (size_t)(dir*TCc + s + 1)*131072;
      #pragma unroll
      for (int e = 0; e < 4; ++e) {
        f32x4 v = *(const f32x4*)(pb + (size_t)(bi*2 + (e>>1))*1024 + n_*16 + ((e&1)*2 + l5)*4);
        accA[4*e+0]=v[0]; accA[4*e+1]=v[1]; accA[4*e+2]=v[2]; accA[4*e+3]=v[3];
      }
    }
    // per-group poll: 64 slots, one load per lane, single ballot
    {
      bool done = false;
      while (!done) {
        int v = __hip_atomic_load(&barr[grp + l], __ATOMIC_RELAXED, __HIP_MEMORY_SCOPE_AGENT);
        done = (__ballot(v >= epoch) == ~0ull);
      }
    }
  }
  #pragma unroll
  for (int e = 0; e < 4; ++e)
    cst[(size_t)(dir*64 + n_)*512 + u0 + 2*e + l5] = cv[e];

  // ---- fused classifier: block 0 waits for all 4 groups ----
  if (doCls && bi == 0) {
    int eEnd = ebase + TCc;
    if (w == 0) {
      bool done = false;
      while (!done) {
        int v0 = __hip_atomic_load(&barr[l],       __ATOMIC_RELAXED, __HIP_MEMORY_SCOPE_AGENT);
        int v1 = __hip_atomic_load(&barr[64 + l],  __ATOMIC_RELAXED, __HIP_MEMORY_SCOPE_AGENT);
        int v2 = __hip_atomic_load(&barr[128 + l], __ATOMIC_RELAXED, __HIP_MEMORY_SCOPE_AGENT);
        int v3 = __hip_atomic_load(&barr[192 + l], __ATOMIC_RELAXED, __HIP_MEMORY_SCOPE_AGENT);
        bool ok = (v0 >= eEnd) && (v1 >= eEnd) && (v2 >= eEnd) && (v3 >= eEnd);
        done = (__ballot(ok) == ~0ull);
      }
    }
    __syncthreads();
    int n = tid >> 2, p = tid & 3;
    const ULL* f0 = (const ULL*)(hF + 32768 + n*512) + p*32;      // fwd h(T-1), phase 1
    const ULL* f1 = (const ULL*)(hF + 3*32768 + n*512) + p*32;    // bwd h(t=0),  phase 1
    float p0 = 0.f, p1 = 0.f, p2 = 0.f;
    for (int j8 = 0; j8 < 32; ++j8) {
      ULL v0 = __hip_atomic_load(f0 + j8, __ATOMIC_RELAXED, __HIP_MEMORY_SCOPE_AGENT);
      ULL v1 = __hip_atomic_load(f1 + j8, __ATOMIC_RELAXED, __HIP_MEMORY_SCOPE_AGENT);
      #pragma unroll
      for (int e = 0; e < 4; ++e) {
        int j = p*128 + j8*4 + e;
        float a  = f16f((ushort)(v0 >> (16*e)));
        float b2 = f16f((ushort)(v1 >> (16*e)));
        p0 += a*Wc[j]        + b2*Wc[512 + j];
        p1 += a*Wc[1024 + j] + b2*Wc[1536 + j];
        p2 += a*Wc[2048 + j] + b2*Wc[2560 + j];
      }
    }
    red[n][p][0] = p0; red[n][p][1] = p1; red[n][p][2] = p2;
    __syncthreads();
    if (tid < 192) {
      int nn = tid / 3, o = tid - nn*3;
      outp[nn*3 + o] = red[nn][0][o] + red[nn][1][o] + red[nn][2][o] + red[nn][3][o] + bc[o];
    }
  }
}

extern "C" void kernel_launch(void* const* d_in, const int* in_sizes, int n_in,
                              void* d_out, int out_size, void* d_ws, size_t ws_size,
                              hipStream_t stream) {
  (void)in_sizes; (void)n_in; (void)out_size;
  const int*   words  = (const int*)d_in[0];
  const int*   chars  = (const int*)d_in[1];
  const float* wl_emb = (const float*)d_in[2];
  const float* cl_emb = (const float*)d_in[3];
  const float* c_wih  = (const float*)d_in[4];
  const float* c_whh  = (const float*)d_in[5];
  const float* c_b    = (const float*)d_in[6];
  const float* WIH[6] = {
    (const float*)d_in[7],  (const float*)d_in[10],
    (const float*)d_in[13], (const float*)d_in[16],
    (const float*)d_in[13] + (size_t)2048*1024, (const float*)d_in[16] + (size_t)2048*1024 };
  const float* WHH[3][2] = {
    { (const float*)d_in[8],  (const float*)d_in[11] },
    { (const float*)d_in[14], (const float*)d_in[17] },
    { (const float*)d_in[14] + (size_t)2048*512, (const float*)d_in[17] + (size_t)2048*512 } };
  const float* BB[6] = {
    (const float*)d_in[9],  (const float*)d_in[12],
    (const float*)d_in[15], (const float*)d_in[18],
    (const float*)d_in[15] + 2048, (const float*)d_in[18] + 2048 };
  const float* Wc = (const float*)d_in[19];
  const float* bc = (const float*)d_in[20];

  // -------- workspace carve --------
  float* wsp = (float*)d_ws;
  size_t off = 0;
  auto carve = [&](size_t nf) { float* p = wsp + off; off += (nf + 63) & ~(size_t)63; return p; };
  ushort* XA = (ushort*)carve((size_t)16384*1024/2);
  ushort* XB = (ushort*)carve((size_t)16384*1024/2);
  ushort* Wh6[6];
  for (int ld = 0; ld < 6; ++ld) {
    size_t D = (ld < 2) ? 320 : 1024;
    Wh6[ld] = (ushort*)carve((size_t)2048*D/2);
  }
  float* bP   = carve(6*2048);
  float* preT = carve(100*256);
  float* whhc = carve(64*256);
  ushort* hF  = (ushort*)carve((size_t)4*32768/2);
  float* cst  = carve((size_t)2*64*512);
  int* barr   = (int*)carve(256);
  size_t wsFloats = ws_size / 4;
  int TCc = 256;
  while (TCc > 16 && off + (size_t)2*TCc*64*2048 > wsFloats) TCc >>= 1;
  float* preg = carve((size_t)2*TCc*64*2048);
  if (off > wsFloats) return;   // insufficient workspace -> loud validation failure

  // -------- node 1: all weight prep (+ barrier-slot zeroing) --------
  PrepArgs pa;
  pa.cl_emb = cl_emb; pa.c_wih = c_wih; pa.c_b = c_b; pa.c_whh = c_whh;
  for (int ld = 0; ld < 6; ++ld) { pa.wih[ld] = WIH[ld]; pa.bb[ld] = BB[ld];
                                   pa.Wh[ld] = Wh6[ld]; }
  pa.preT = preT; pa.whhc = whhc; pa.bP = bP; pa.barr = barr;
  k_prep<<<9684, 256, 0, stream>>>(pa);

  // -------- node 2: word embedding + char LSTM --------
  k_wordchar<<<16640, 256, 0, stream>>>(words, chars, wl_emb, preT, whhc, XA);

  // -------- 3 stacked BiLSTM layers --------
  for (int l = 0; l < 3; ++l) {
    const ushort* Xin = (l == 1) ? XB : XA;
    ushort* Xout = (l == 0) ? XB : ((l == 1) ? XA : nullptr);
    int D = l ? 1024 : 320;
    for (int t0 = 0; t0 < T_; t0 += TCc) {
      k_gemm<<<dim3(TCc/2, 16, 2), 256, 0, stream>>>(Xin,
          Wh6[2*l], Wh6[2*l+1],
          bP + (2*l)*2048, bP + (2*l+1)*2048, preg, D, t0, TCc);
      int doCls = (l == 2 && t0 + TCc == T_) ? 1 : 0;
      k_rec<<<64, 256, 0, stream>>>(preg, WHH[l][0], WHH[l][1], Xout, hF, cst,
                                    barr, t0, TCc, l*T_ + t0, doCls, Wc, bc, (float*)d_out);
    }
  }
}